// Round 4
// baseline (900.023 us; speedup 1.0000x reference)
//
#include <hip/hip_runtime.h>
#include <hip/hip_fp16.h>

#define NLEVELS 8
#define NBANDS  64
#define CHUNK   4096   // samples per block in scatter/main (16 iters x 256 threads)

// RESOLUTIONS = [16, 29, 53, 98, 181, 332, 610, 1120]
__constant__ int   c_res[NLEVELS]   = {16, 29, 53, 98, 181, 332, 610, 1120};
__constant__ float c_scale[NLEVELS] = {7.5f, 14.0f, 26.0f, 48.5f, 90.0f, 165.5f, 304.5f, 559.5f};
__constant__ int   c_cum[NLEVELS]   = {0, 256, 1097, 3906, 13510, 46271, 156495, 528595};
#define TOTAL_TEXELS 1782995

typedef float        f32x4 __attribute__((ext_vector_type(4)));
typedef float        f32x2 __attribute__((ext_vector_type(2)));
typedef unsigned int u32;
typedef u32          u32x4 __attribute__((ext_vector_type(4), aligned(8)));  // 8-B-aligned 16-B load

struct CbPtrs { const float* cb[NLEVELS]; };

__device__ __forceinline__ float2 up_h2(u32 v) {
    __half2 h = *reinterpret_cast<__half2*>(&v);
    return __half22float2(h);
}

__device__ __forceinline__ int band_of(float cy) {
    float v = (cy + 1.0f) * 0.5f;
    int k = (int)(v * (float)NBANDS);
    return min(NBANDS - 1, max(0, k));
}

// ---------------- transpose [4,R,R] fp32 -> [R,R,4] fp16 texels (8B uint2) ----------------
__global__ __launch_bounds__(256) void transpose_cbs(CbPtrs p, uint2* __restrict__ tcb, int total) {
    for (int t = blockIdx.x * blockDim.x + threadIdx.x; t < total; t += gridDim.x * blockDim.x) {
        int L = 0;
#pragma unroll
        for (int i = 1; i < NLEVELS; ++i) if (t >= c_cum[i]) L = i;
        int i  = t - c_cum[L];
        int rr = c_res[L] * c_res[L];
        const float* cb = p.cb[L];
        __half2 h01 = __floats2half2_rn(cb[i],          cb[i + rr]);
        __half2 h23 = __floats2half2_rn(cb[i + 2 * rr], cb[i + 3 * rr]);
        uint2 tex;
        tex.x = *reinterpret_cast<u32*>(&h01);
        tex.y = *reinterpret_cast<u32*>(&h23);
        tcb[t] = tex;
    }
}

// ---------------- binning ----------------
__global__ __launch_bounds__(64) void zero_counts(u32* gcount) {
    gcount[threadIdx.x] = 0u;
}

__global__ __launch_bounds__(256) void hist_kernel(const float2* __restrict__ coords,
                                                   u32* __restrict__ gcount, int S) {
    __shared__ u32 h[NBANDS];
    for (int i = threadIdx.x; i < NBANDS; i += 256) h[i] = 0u;
    __syncthreads();
    for (int s = blockIdx.x * 256 + threadIdx.x; s < S; s += gridDim.x * 256)
        atomicAdd(&h[band_of(coords[s].y)], 1u);
    __syncthreads();
    for (int i = threadIdx.x; i < NBANDS; i += 256)
        if (h[i]) atomicAdd(&gcount[i], h[i]);
}

__global__ __launch_bounds__(64) void scan_kernel(const u32* __restrict__ gcount,
                                                  u32* __restrict__ gcursor) {
    if (threadIdx.x == 0) {
        u32 acc = 0;
        for (int i = 0; i < NBANDS; ++i) { gcursor[i] = acc; acc += gcount[i]; }
    }
}

__global__ __launch_bounds__(256) void scatter_kernel(const float2* __restrict__ coords,
                                                      u32* __restrict__ gcursor,
                                                      float2* __restrict__ coordsS,
                                                      int*    __restrict__ idxS, int S) {
    __shared__ u32 h[NBANDS];
    __shared__ u32 rank_base[NBANDS];
    int s0 = blockIdx.x * CHUNK;
    for (int i = threadIdx.x; i < NBANDS; i += 256) h[i] = 0u;
    __syncthreads();
    u32 myrank[CHUNK / 256];
    int myk[CHUNK / 256];
    float2 myc[CHUNK / 256];
#pragma unroll
    for (int it = 0; it < CHUNK / 256; ++it) {
        int s = s0 + it * 256 + threadIdx.x;
        if (s < S) {
            float2 c = coords[s];
            int k = band_of(c.y);
            myc[it] = c;
            myk[it] = k;
            myrank[it] = atomicAdd(&h[k], 1u);
        }
    }
    __syncthreads();
    for (int i = threadIdx.x; i < NBANDS; i += 256)
        rank_base[i] = h[i] ? atomicAdd(&gcursor[i], h[i]) : 0u;
    __syncthreads();
#pragma unroll
    for (int it = 0; it < CHUNK / 256; ++it) {
        int s = s0 + it * 256 + threadIdx.x;
        if (s < S) {
            u32 pos = rank_base[myk[it]] + myrank[it];
            coordsS[pos] = myc[it];
            idxS[pos]    = s;
        }
    }
}

// ---------------- main: band-sorted samples, sample-per-thread, all 8 levels ----------------
__global__ __launch_bounds__(256) void grid_sorted(const f32x2* __restrict__ coordsS,
                                                   const int*    __restrict__ idxS,
                                                   const uint2*  __restrict__ tcb,
                                                   f32x4* __restrict__ out, int S) {
    // XCD-contiguous swizzle: physical block p runs on XCD p%8; give each XCD a
    // contiguous logical range so its concurrent fine-level working set is ~1/8.
    int p  = blockIdx.x;
    int nb = gridDim.x;                  // multiple of 8
    int b  = (p & 7) * (nb >> 3) + (p >> 3);
    int s0 = b * CHUNK;
#pragma unroll 1
    for (int it = 0; it < CHUNK / 256; ++it) {
        int s = s0 + it * 256 + threadIdx.x;
        if (s >= S) break;
        f32x2 c = __builtin_nontemporal_load(&coordsS[s]);
        int idx = __builtin_nontemporal_load(&idxS[s]);
        f32x4* o = out + (size_t)idx * 8;
#pragma unroll
        for (int L = 0; L < NLEVELS; ++L) {
            int   res   = c_res[L];
            float scale = c_scale[L];
            const uint2* __restrict__ base = tcb + c_cum[L];
            float px = (c.x + 1.0f) * scale;
            float py = (c.y + 1.0f) * scale;
            float xf = floorf(px), yf = floorf(py);
            float wx = px - xf,    wy = py - yf;
            int x0 = (int)xf, y0 = (int)yf;
            // coords are in [-1,1) so px,py in [0,res-1); pair base never clamps in
            // practice, but keep it safe: shift pair left and move the weight right.
            int xp = min(max(x0, 0), res - 2);  wx += (float)(x0 - xp);
            int yp = min(max(y0, 0), res - 2);  wy += (float)(y0 - yp);
            const uint2* r0 = base + yp * res + xp;
            u32x4 t0 = *(const u32x4*)r0;          // texels (xp,yp),(xp+1,yp)
            u32x4 t1 = *(const u32x4*)(r0 + res);  // texels (xp,yp+1),(xp+1,yp+1)
            float2 a00 = up_h2(t0.x), b00 = up_h2(t0.y);
            float2 a01 = up_h2(t0.z), b01 = up_h2(t0.w);
            float2 a10 = up_h2(t1.x), b10 = up_h2(t1.y);
            float2 a11 = up_h2(t1.z), b11 = up_h2(t1.w);
            float w00 = (1.0f - wx) * (1.0f - wy);
            float w01 = wx * (1.0f - wy);
            float w10 = (1.0f - wx) * wy;
            float w11 = wx * wy;
            f32x4 r;
            r.x = a00.x * w00 + a01.x * w01 + a10.x * w10 + a11.x * w11;
            r.y = a00.y * w00 + a01.y * w01 + a10.y * w10 + a11.y * w11;
            r.z = b00.x * w00 + b01.x * w01 + b10.x * w10 + b11.x * w11;
            r.w = b00.y * w00 + b01.y * w01 + b10.y * w10 + b11.y * w11;
            __builtin_nontemporal_store(r, &o[L]);
        }
    }
}

// ---------------- unsorted fallback (ws too small for bins) ----------------
__global__ __launch_bounds__(256) void grid_main(const float2* __restrict__ coords,
                                                 const uint2* __restrict__ tcb,
                                                 f32x4* __restrict__ out4, int S) {
    int t = blockIdx.x * 256 + threadIdx.x;
    if (t >= S * 8) return;
    int L = t & 7;
    int s = t >> 3;
    float2 c = coords[s];
    int   res   = c_res[L];
    float scale = c_scale[L];
    const uint2* __restrict__ base = tcb + c_cum[L];
    float px = (c.x + 1.0f) * scale;
    float py = (c.y + 1.0f) * scale;
    float xf = floorf(px), yf = floorf(py);
    float wx = px - xf,    wy = py - yf;
    int x0 = (int)xf, y0 = (int)yf;
    int xp = min(max(x0, 0), res - 2);  wx += (float)(x0 - xp);
    int yp = min(max(y0, 0), res - 2);  wy += (float)(y0 - yp);
    const uint2* r0 = base + yp * res + xp;
    u32x4 t0 = *(const u32x4*)r0;
    u32x4 t1 = *(const u32x4*)(r0 + res);
    float2 a00 = up_h2(t0.x), b00 = up_h2(t0.y);
    float2 a01 = up_h2(t0.z), b01 = up_h2(t0.w);
    float2 a10 = up_h2(t1.x), b10 = up_h2(t1.y);
    float2 a11 = up_h2(t1.z), b11 = up_h2(t1.w);
    float w00 = (1.0f - wx) * (1.0f - wy);
    float w01 = wx * (1.0f - wy);
    float w10 = (1.0f - wx) * wy;
    float w11 = wx * wy;
    f32x4 r;
    r.x = a00.x * w00 + a01.x * w01 + a10.x * w10 + a11.x * w11;
    r.y = a00.y * w00 + a01.y * w01 + a10.y * w10 + a11.y * w11;
    r.z = b00.x * w00 + b01.x * w01 + b10.x * w10 + b11.x * w11;
    r.w = b00.y * w00 + b01.y * w01 + b10.y * w10 + b11.y * w11;
    __builtin_nontemporal_store(r, &out4[t]);
}

// ---------------- generic levels fallback (levels != 8, raw fp32 cbs) ----------------
__global__ __launch_bounds__(256) void grid_generic(const float2* __restrict__ coords,
                                                    CbPtrs p, float4* __restrict__ out4,
                                                    int S, int levels) {
    int s = blockIdx.x * 256 + threadIdx.x;
    if (s >= S) return;
    float2 c = coords[s];
    for (int L = 0; L < levels; ++L) {
        int   res   = c_res[L];
        float scale = c_scale[L];
        float px = (c.x + 1.0f) * scale;
        float py = (c.y + 1.0f) * scale;
        float x0f = floorf(px), y0f = floorf(py);
        float wx = px - x0f,    wy = py - y0f;
        int rm1 = res - 1;
        int x0 = min(max((int)x0f, 0), rm1);
        int x1 = min(x0 + 1, rm1);
        int y0 = min(max((int)y0f, 0), rm1);
        int y1 = min(y0 + 1, rm1);
        int i00 = y0 * res + x0, i01 = y0 * res + x1, i10 = y1 * res + x0, i11 = y1 * res + x1;
        float w00 = (1.0f - wx) * (1.0f - wy);
        float w01 = wx * (1.0f - wy);
        float w10 = (1.0f - wx) * wy;
        float w11 = wx * wy;
        float4 r;
        const float* cb = p.cb[L];
        int rr = res * res;
        float* pr = &r.x;
#pragma unroll
        for (int f = 0; f < 4; ++f) {
            const float* cf = cb + f * rr;
            pr[f] = cf[i00] * w00 + cf[i01] * w01 + cf[i10] * w10 + cf[i11] * w11;
        }
        out4[(size_t)s * levels + L] = r;
    }
}

extern "C" void kernel_launch(void* const* d_in, const int* in_sizes, int n_in,
                              void* d_out, int out_size, void* d_ws, size_t ws_size,
                              hipStream_t stream) {
    const float2* coords = (const float2*)d_in[0];
    int S = in_sizes[0] / 2;                 // total samples B*N
    int levels = out_size / (S * 4);

    CbPtrs ptrs;
    for (int i = 0; i < NLEVELS; ++i) ptrs.cb[i] = (const float*)d_in[2 + i];

    // ws layout
    size_t tcb_bytes  = ((size_t)TOTAL_TEXELS * 8 + 255) & ~(size_t)255;
    size_t cnt_bytes  = 1024;                       // gcount[64] + gcursor[64]
    size_t crd_bytes  = (size_t)S * 8;
    size_t idx_bytes  = (size_t)S * 4;
    size_t need_sorted = tcb_bytes + cnt_bytes + crd_bytes + idx_bytes;

    char* ws = (char*)d_ws;
    uint2*  tcb     = (uint2*)ws;
    u32*    gcount  = (u32*)(ws + tcb_bytes);
    u32*    gcursor = gcount + NBANDS;
    float2* coordsS = (float2*)(ws + tcb_bytes + cnt_bytes);
    int*    idxS    = (int*)(ws + tcb_bytes + cnt_bytes + crd_bytes);

    if (levels != NLEVELS) {
        int blocks = (S + 255) / 256;
        grid_generic<<<blocks, 256, 0, stream>>>(coords, ptrs, (float4*)d_out, S, levels);
        return;
    }
    if (ws_size < tcb_bytes) {
        int blocks = (S + 255) / 256;
        grid_generic<<<blocks, 256, 0, stream>>>(coords, ptrs, (float4*)d_out, S, levels);
        return;
    }

    int tg = (TOTAL_TEXELS + 255) / 256;
    transpose_cbs<<<tg, 256, 0, stream>>>(ptrs, tcb, TOTAL_TEXELS);

    if (ws_size >= need_sorted) {
        int nchunk = (S + CHUNK - 1) / CHUNK;
        int nb     = ((nchunk + 7) / 8) * 8;        // multiple of 8 for bijective swizzle
        zero_counts<<<1, 64, 0, stream>>>(gcount);
        hist_kernel<<<512, 256, 0, stream>>>(coords, gcount, S);
        scan_kernel<<<1, 64, 0, stream>>>(gcount, gcursor);
        scatter_kernel<<<nchunk, 256, 0, stream>>>(coords, gcursor, coordsS, idxS, S);
        grid_sorted<<<nb, 256, 0, stream>>>((const f32x2*)coordsS, idxS, tcb, (f32x4*)d_out, S);
    } else {
        int total  = S * 8;
        int blocks = (total + 255) / 256;
        grid_main<<<blocks, 256, 0, stream>>>(coords, tcb, (f32x4*)d_out, S);
    }
}

// Round 5
// 276.897 us; speedup vs baseline: 3.2504x; 3.2504x over previous
//
#include <hip/hip_runtime.h>
#include <hip/hip_fp16.h>

#define NLEVELS 8
#define NBANDS  64
#define CHUNK   1024   // samples per block in scatter/main (4 iters x 256 threads)

// RESOLUTIONS = [16, 29, 53, 98, 181, 332, 610, 1120]
__constant__ int   c_res[NLEVELS]   = {16, 29, 53, 98, 181, 332, 610, 1120};
__constant__ float c_scale[NLEVELS] = {7.5f, 14.0f, 26.0f, 48.5f, 90.0f, 165.5f, 304.5f, 559.5f};
__constant__ int   c_cum[NLEVELS]   = {0, 256, 1097, 3906, 13510, 46271, 156495, 528595};
#define TOTAL_TEXELS 1782995

typedef float        f32x4 __attribute__((ext_vector_type(4)));
typedef float        f32x2 __attribute__((ext_vector_type(2)));
typedef unsigned int u32;
typedef u32          u32x4 __attribute__((ext_vector_type(4), aligned(8)));  // 8-B-aligned 16-B load

struct CbPtrs { const float* cb[NLEVELS]; };

__device__ __forceinline__ float2 up_h2(u32 v) {
    __half2 h = *reinterpret_cast<__half2*>(&v);
    return __half22float2(h);
}

__device__ __forceinline__ int band_of(float cy) {
    float v = (cy + 1.0f) * 0.5f;
    int k = (int)(v * (float)NBANDS);
    return min(NBANDS - 1, max(0, k));
}

// ---------------- transpose [4,R,R] fp32 -> [R,R,4] fp16 texels (8B uint2) ----------------
__global__ __launch_bounds__(256) void transpose_cbs(CbPtrs p, uint2* __restrict__ tcb, int total) {
    for (int t = blockIdx.x * blockDim.x + threadIdx.x; t < total; t += gridDim.x * blockDim.x) {
        int L = 0;
#pragma unroll
        for (int i = 1; i < NLEVELS; ++i) if (t >= c_cum[i]) L = i;
        int i  = t - c_cum[L];
        int rr = c_res[L] * c_res[L];
        const float* cb = p.cb[L];
        __half2 h01 = __floats2half2_rn(cb[i],          cb[i + rr]);
        __half2 h23 = __floats2half2_rn(cb[i + 2 * rr], cb[i + 3 * rr]);
        uint2 tex;
        tex.x = *reinterpret_cast<u32*>(&h01);
        tex.y = *reinterpret_cast<u32*>(&h23);
        tcb[t] = tex;
    }
}

// ---------------- binning ----------------
__global__ __launch_bounds__(64) void zero_counts(u32* gcount) {
    gcount[threadIdx.x] = 0u;
}

__global__ __launch_bounds__(256) void hist_kernel(const float2* __restrict__ coords,
                                                   u32* __restrict__ gcount, int S) {
    __shared__ u32 h[NBANDS];
    for (int i = threadIdx.x; i < NBANDS; i += 256) h[i] = 0u;
    __syncthreads();
    for (int s = blockIdx.x * 256 + threadIdx.x; s < S; s += gridDim.x * 256)
        atomicAdd(&h[band_of(coords[s].y)], 1u);
    __syncthreads();
    for (int i = threadIdx.x; i < NBANDS; i += 256)
        if (h[i]) atomicAdd(&gcount[i], h[i]);
}

__global__ __launch_bounds__(64) void scan_kernel(const u32* __restrict__ gcount,
                                                  u32* __restrict__ gcursor) {
    if (threadIdx.x == 0) {
        u32 acc = 0;
        for (int i = 0; i < NBANDS; ++i) { gcursor[i] = acc; acc += gcount[i]; }
    }
}

__global__ __launch_bounds__(256) void scatter_kernel(const float2* __restrict__ coords,
                                                      u32* __restrict__ gcursor,
                                                      float2* __restrict__ coordsS,
                                                      int*    __restrict__ idxS, int S) {
    __shared__ u32 h[NBANDS];
    __shared__ u32 rank_base[NBANDS];
    int s0 = blockIdx.x * CHUNK;
    for (int i = threadIdx.x; i < NBANDS; i += 256) h[i] = 0u;
    __syncthreads();
    u32 myrank[CHUNK / 256];
    int myk[CHUNK / 256];
    float2 myc[CHUNK / 256];
#pragma unroll
    for (int it = 0; it < CHUNK / 256; ++it) {
        int s = s0 + it * 256 + threadIdx.x;
        if (s < S) {
            float2 c = coords[s];
            int k = band_of(c.y);
            myc[it] = c;
            myk[it] = k;
            myrank[it] = atomicAdd(&h[k], 1u);
        }
    }
    __syncthreads();
    for (int i = threadIdx.x; i < NBANDS; i += 256)
        rank_base[i] = h[i] ? atomicAdd(&gcursor[i], h[i]) : 0u;
    __syncthreads();
#pragma unroll
    for (int it = 0; it < CHUNK / 256; ++it) {
        int s = s0 + it * 256 + threadIdx.x;
        if (s < S) {
            u32 pos = rank_base[myk[it]] + myrank[it];
            coordsS[pos] = myc[it];
            idxS[pos]    = s;
        }
    }
}

// ---------------- main: band-sorted samples, sample-per-thread, all 8 levels ----------------
__global__ __launch_bounds__(256) void grid_sorted(const f32x2* __restrict__ coordsS,
                                                   const int*    __restrict__ idxS,
                                                   const uint2*  __restrict__ tcb,
                                                   f32x4* __restrict__ out, int S) {
    // XCD-contiguous swizzle: physical block p runs on XCD p%8; give each XCD a
    // contiguous logical range so its concurrent fine-level working set is ~1/8.
    int p  = blockIdx.x;
    int nb = gridDim.x;                  // multiple of 8
    int b  = (p & 7) * (nb >> 3) + (p >> 3);
    int s0 = b * CHUNK;
#pragma unroll 1
    for (int it = 0; it < CHUNK / 256; ++it) {
        int s = s0 + it * 256 + threadIdx.x;
        if (s >= S) break;
        f32x2 c = __builtin_nontemporal_load(&coordsS[s]);
        int idx = __builtin_nontemporal_load(&idxS[s]);
        f32x4* o = out + (size_t)idx * 8;
#pragma unroll
        for (int L = 0; L < NLEVELS; ++L) {
            int   res   = c_res[L];
            float scale = c_scale[L];
            const uint2* __restrict__ base = tcb + c_cum[L];
            float px = (c.x + 1.0f) * scale;
            float py = (c.y + 1.0f) * scale;
            float xf = floorf(px), yf = floorf(py);
            float wx = px - xf,    wy = py - yf;
            int x0 = (int)xf, y0 = (int)yf;
            int xp = min(max(x0, 0), res - 2);  wx += (float)(x0 - xp);
            int yp = min(max(y0, 0), res - 2);  wy += (float)(y0 - yp);
            const uint2* r0 = base + yp * res + xp;
            u32x4 t0 = *(const u32x4*)r0;          // texels (xp,yp),(xp+1,yp)
            u32x4 t1 = *(const u32x4*)(r0 + res);  // texels (xp,yp+1),(xp+1,yp+1)
            float2 a00 = up_h2(t0.x), b00 = up_h2(t0.y);
            float2 a01 = up_h2(t0.z), b01 = up_h2(t0.w);
            float2 a10 = up_h2(t1.x), b10 = up_h2(t1.y);
            float2 a11 = up_h2(t1.z), b11 = up_h2(t1.w);
            float w00 = (1.0f - wx) * (1.0f - wy);
            float w01 = wx * (1.0f - wy);
            float w10 = (1.0f - wx) * wy;
            float w11 = wx * wy;
            f32x4 r;
            r.x = a00.x * w00 + a01.x * w01 + a10.x * w10 + a11.x * w11;
            r.y = a00.y * w00 + a01.y * w01 + a10.y * w10 + a11.y * w11;
            r.z = b00.x * w00 + b01.x * w01 + b10.x * w10 + b11.x * w11;
            r.w = b00.y * w00 + b01.y * w01 + b10.y * w10 + b11.y * w11;
            o[L] = r;   // regular store: let L2 merge the 128B/sample into full lines
        }
    }
}

// ---------------- unsorted fallback (ws too small for bins) ----------------
__global__ __launch_bounds__(256) void grid_main(const float2* __restrict__ coords,
                                                 const uint2* __restrict__ tcb,
                                                 f32x4* __restrict__ out4, int S) {
    int t = blockIdx.x * 256 + threadIdx.x;
    if (t >= S * 8) return;
    int L = t & 7;
    int s = t >> 3;
    float2 c = coords[s];
    int   res   = c_res[L];
    float scale = c_scale[L];
    const uint2* __restrict__ base = tcb + c_cum[L];
    float px = (c.x + 1.0f) * scale;
    float py = (c.y + 1.0f) * scale;
    float xf = floorf(px), yf = floorf(py);
    float wx = px - xf,    wy = py - yf;
    int x0 = (int)xf, y0 = (int)yf;
    int xp = min(max(x0, 0), res - 2);  wx += (float)(x0 - xp);
    int yp = min(max(y0, 0), res - 2);  wy += (float)(y0 - yp);
    const uint2* r0 = base + yp * res + xp;
    u32x4 t0 = *(const u32x4*)r0;
    u32x4 t1 = *(const u32x4*)(r0 + res);
    float2 a00 = up_h2(t0.x), b00 = up_h2(t0.y);
    float2 a01 = up_h2(t0.z), b01 = up_h2(t0.w);
    float2 a10 = up_h2(t1.x), b10 = up_h2(t1.y);
    float2 a11 = up_h2(t1.z), b11 = up_h2(t1.w);
    float w00 = (1.0f - wx) * (1.0f - wy);
    float w01 = wx * (1.0f - wy);
    float w10 = (1.0f - wx) * wy;
    float w11 = wx * wy;
    f32x4 r;
    r.x = a00.x * w00 + a01.x * w01 + a10.x * w10 + a11.x * w11;
    r.y = a00.y * w00 + a01.y * w01 + a10.y * w10 + a11.y * w11;
    r.z = b00.x * w00 + b01.x * w01 + b10.x * w10 + b11.x * w11;
    r.w = b00.y * w00 + b01.y * w01 + b10.y * w10 + b11.y * w11;
    __builtin_nontemporal_store(r, &out4[t]);
}

// ---------------- generic levels fallback (levels != 8, raw fp32 cbs) ----------------
__global__ __launch_bounds__(256) void grid_generic(const float2* __restrict__ coords,
                                                    CbPtrs p, float4* __restrict__ out4,
                                                    int S, int levels) {
    int s = blockIdx.x * 256 + threadIdx.x;
    if (s >= S) return;
    float2 c = coords[s];
    for (int L = 0; L < levels; ++L) {
        int   res   = c_res[L];
        float scale = c_scale[L];
        float px = (c.x + 1.0f) * scale;
        float py = (c.y + 1.0f) * scale;
        float x0f = floorf(px), y0f = floorf(py);
        float wx = px - x0f,    wy = py - y0f;
        int rm1 = res - 1;
        int x0 = min(max((int)x0f, 0), rm1);
        int x1 = min(x0 + 1, rm1);
        int y0 = min(max((int)y0f, 0), rm1);
        int y1 = min(y0 + 1, rm1);
        int i00 = y0 * res + x0, i01 = y0 * res + x1, i10 = y1 * res + x0, i11 = y1 * res + x1;
        float w00 = (1.0f - wx) * (1.0f - wy);
        float w01 = wx * (1.0f - wy);
        float w10 = (1.0f - wx) * wy;
        float w11 = wx * wy;
        float4 r;
        const float* cb = p.cb[L];
        int rr = res * res;
        float* pr = &r.x;
#pragma unroll
        for (int f = 0; f < 4; ++f) {
            const float* cf = cb + f * rr;
            pr[f] = cf[i00] * w00 + cf[i01] * w01 + cf[i10] * w10 + cf[i11] * w11;
        }
        out4[(size_t)s * levels + L] = r;
    }
}

extern "C" void kernel_launch(void* const* d_in, const int* in_sizes, int n_in,
                              void* d_out, int out_size, void* d_ws, size_t ws_size,
                              hipStream_t stream) {
    const float2* coords = (const float2*)d_in[0];
    int S = in_sizes[0] / 2;                 // total samples B*N
    int levels = out_size / (S * 4);

    CbPtrs ptrs;
    for (int i = 0; i < NLEVELS; ++i) ptrs.cb[i] = (const float*)d_in[2 + i];

    // ws layout
    size_t tcb_bytes  = ((size_t)TOTAL_TEXELS * 8 + 255) & ~(size_t)255;
    size_t cnt_bytes  = 1024;                       // gcount[64] + gcursor[64]
    size_t crd_bytes  = (size_t)S * 8;
    size_t idx_bytes  = (size_t)S * 4;
    size_t need_sorted = tcb_bytes + cnt_bytes + crd_bytes + idx_bytes;

    char* ws = (char*)d_ws;
    uint2*  tcb     = (uint2*)ws;
    u32*    gcount  = (u32*)(ws + tcb_bytes);
    u32*    gcursor = gcount + NBANDS;
    float2* coordsS = (float2*)(ws + tcb_bytes + cnt_bytes);
    int*    idxS    = (int*)(ws + tcb_bytes + cnt_bytes + crd_bytes);

    if (levels != NLEVELS) {
        int blocks = (S + 255) / 256;
        grid_generic<<<blocks, 256, 0, stream>>>(coords, ptrs, (float4*)d_out, S, levels);
        return;
    }
    if (ws_size < tcb_bytes) {
        int blocks = (S + 255) / 256;
        grid_generic<<<blocks, 256, 0, stream>>>(coords, ptrs, (float4*)d_out, S, levels);
        return;
    }

    int tg = (TOTAL_TEXELS + 255) / 256;
    transpose_cbs<<<tg, 256, 0, stream>>>(ptrs, tcb, TOTAL_TEXELS);

    if (ws_size >= need_sorted) {
        int nchunk = (S + CHUNK - 1) / CHUNK;
        int nb     = ((nchunk + 7) / 8) * 8;        // multiple of 8 for bijective swizzle
        zero_counts<<<1, 64, 0, stream>>>(gcount);
        hist_kernel<<<512, 256, 0, stream>>>(coords, gcount, S);
        scan_kernel<<<1, 64, 0, stream>>>(gcount, gcursor);
        scatter_kernel<<<nchunk, 256, 0, stream>>>(coords, gcursor, coordsS, idxS, S);
        grid_sorted<<<nb, 256, 0, stream>>>((const f32x2*)coordsS, idxS, tcb, (f32x4*)d_out, S);
    } else {
        int total  = S * 8;
        int blocks = (total + 255) / 256;
        grid_main<<<blocks, 256, 0, stream>>>(coords, tcb, (f32x4*)d_out, S);
    }
}

// Round 6
// 179.277 us; speedup vs baseline: 5.0203x; 1.5445x over previous
//
#include <hip/hip_runtime.h>
#include <hip/hip_fp16.h>

#define NLEVELS 8
#define NBANDS  64
#define CHUNK   1024   // samples per block in scatter (4 iters x 256 threads)

// RESOLUTIONS = [16, 29, 53, 98, 181, 332, 610, 1120]
__constant__ int   c_res[NLEVELS]   = {16, 29, 53, 98, 181, 332, 610, 1120};
__constant__ float c_scale[NLEVELS] = {7.5f, 14.0f, 26.0f, 48.5f, 90.0f, 165.5f, 304.5f, 559.5f};
__constant__ int   c_cum[NLEVELS]   = {0, 256, 1097, 3906, 13510, 46271, 156495, 528595};
#define TOTAL_TEXELS 1782995

typedef float        f32x4 __attribute__((ext_vector_type(4)));
typedef float        f32x2 __attribute__((ext_vector_type(2)));
typedef unsigned int u32;
typedef u32          u32x4 __attribute__((ext_vector_type(4), aligned(8)));  // 8-B-aligned 16-B load

struct CbPtrs { const float* cb[NLEVELS]; };

__device__ __forceinline__ float2 up_h2(u32 v) {
    __half2 h = *reinterpret_cast<__half2*>(&v);
    return __half22float2(h);
}

__device__ __forceinline__ int band_of(float cy) {
    float v = (cy + 1.0f) * 0.5f;
    int k = (int)(v * (float)NBANDS);
    return min(NBANDS - 1, max(0, k));
}

// ---------------- transpose [4,R,R] fp32 -> [R,R,4] fp16 texels (8B uint2) ----------------
__global__ __launch_bounds__(256) void transpose_cbs(CbPtrs p, uint2* __restrict__ tcb, int total) {
    for (int t = blockIdx.x * blockDim.x + threadIdx.x; t < total; t += gridDim.x * blockDim.x) {
        int L = 0;
#pragma unroll
        for (int i = 1; i < NLEVELS; ++i) if (t >= c_cum[i]) L = i;
        int i  = t - c_cum[L];
        int rr = c_res[L] * c_res[L];
        const float* cb = p.cb[L];
        __half2 h01 = __floats2half2_rn(cb[i],          cb[i + rr]);
        __half2 h23 = __floats2half2_rn(cb[i + 2 * rr], cb[i + 3 * rr]);
        uint2 tex;
        tex.x = *reinterpret_cast<u32*>(&h01);
        tex.y = *reinterpret_cast<u32*>(&h23);
        tcb[t] = tex;
    }
}

// ---------------- binning ----------------
__global__ __launch_bounds__(64) void zero_counts(u32* gcount) {
    gcount[threadIdx.x] = 0u;
}

__global__ __launch_bounds__(256) void hist_kernel(const float2* __restrict__ coords,
                                                   u32* __restrict__ gcount, int S) {
    __shared__ u32 h[NBANDS];
    for (int i = threadIdx.x; i < NBANDS; i += 256) h[i] = 0u;
    __syncthreads();
    for (int s = blockIdx.x * 256 + threadIdx.x; s < S; s += gridDim.x * 256)
        atomicAdd(&h[band_of(coords[s].y)], 1u);
    __syncthreads();
    for (int i = threadIdx.x; i < NBANDS; i += 256)
        if (h[i]) atomicAdd(&gcount[i], h[i]);
}

__global__ __launch_bounds__(64) void scan_kernel(const u32* __restrict__ gcount,
                                                  u32* __restrict__ gcursor) {
    if (threadIdx.x == 0) {
        u32 acc = 0;
        for (int i = 0; i < NBANDS; ++i) { gcursor[i] = acc; acc += gcount[i]; }
    }
}

__global__ __launch_bounds__(256) void scatter_kernel(const float2* __restrict__ coords,
                                                      u32* __restrict__ gcursor,
                                                      float2* __restrict__ coordsS,
                                                      int*    __restrict__ idxS, int S) {
    __shared__ u32 h[NBANDS];
    __shared__ u32 rank_base[NBANDS];
    int s0 = blockIdx.x * CHUNK;
    for (int i = threadIdx.x; i < NBANDS; i += 256) h[i] = 0u;
    __syncthreads();
    u32 myrank[CHUNK / 256];
    int myk[CHUNK / 256];
    float2 myc[CHUNK / 256];
#pragma unroll
    for (int it = 0; it < CHUNK / 256; ++it) {
        int s = s0 + it * 256 + threadIdx.x;
        if (s < S) {
            float2 c = coords[s];
            int k = band_of(c.y);
            myc[it] = c;
            myk[it] = k;
            myrank[it] = atomicAdd(&h[k], 1u);
        }
    }
    __syncthreads();
    for (int i = threadIdx.x; i < NBANDS; i += 256)
        rank_base[i] = h[i] ? atomicAdd(&gcursor[i], h[i]) : 0u;
    __syncthreads();
#pragma unroll
    for (int it = 0; it < CHUNK / 256; ++it) {
        int s = s0 + it * 256 + threadIdx.x;
        if (s < S) {
            u32 pos = rank_base[myk[it]] + myrank[it];
            coordsS[pos] = myc[it];
            idxS[pos]    = s;
        }
    }
}

// ------- main: band-sorted samples, 8 threads per sample (one per level) -------
// Lanes 8k..8k+7 share sample s: store instruction covers 8 samples x 128 B
// contiguous -> full-line coalesced writes. Gathers keep sorted L2 locality.
__global__ __launch_bounds__(256) void grid_sorted8(const f32x2* __restrict__ coordsS,
                                                    const int*   __restrict__ idxS,
                                                    const uint2* __restrict__ tcb,
                                                    f32x4* __restrict__ out, int S) {
    // XCD-contiguous swizzle: physical block p runs on XCD p%8; give each XCD a
    // contiguous logical range so its concurrent working set is ~1/8 of the sort.
    int p  = blockIdx.x;
    int nb = gridDim.x;                  // multiple of 8
    int b  = (p & 7) * (nb >> 3) + (p >> 3);
    int t  = b * 256 + threadIdx.x;
    int s  = t >> 3;
    if (s >= S) return;
    int L  = t & 7;

    f32x2 c = coordsS[s];                // 8 lanes hit the same 8-B coord (L1 broadcast)
    int idx = idxS[s];

    int   res   = c_res[L];
    float scale = c_scale[L];
    const uint2* __restrict__ base = tcb + c_cum[L];

    float px = (c.x + 1.0f) * scale;
    float py = (c.y + 1.0f) * scale;
    float xf = floorf(px), yf = floorf(py);
    float wx = px - xf,    wy = py - yf;
    int x0 = (int)xf, y0 = (int)yf;
    int xp = min(max(x0, 0), res - 2);  wx += (float)(x0 - xp);
    int yp = min(max(y0, 0), res - 2);  wy += (float)(y0 - yp);
    const uint2* r0 = base + yp * res + xp;
    u32x4 t0 = *(const u32x4*)r0;          // texels (xp,yp),(xp+1,yp)
    u32x4 t1 = *(const u32x4*)(r0 + res);  // texels (xp,yp+1),(xp+1,yp+1)

    float2 a00 = up_h2(t0.x), b00 = up_h2(t0.y);
    float2 a01 = up_h2(t0.z), b01 = up_h2(t0.w);
    float2 a10 = up_h2(t1.x), b10 = up_h2(t1.y);
    float2 a11 = up_h2(t1.z), b11 = up_h2(t1.w);

    float w00 = (1.0f - wx) * (1.0f - wy);
    float w01 = wx * (1.0f - wy);
    float w10 = (1.0f - wx) * wy;
    float w11 = wx * wy;

    f32x4 r;
    r.x = a00.x * w00 + a01.x * w01 + a10.x * w10 + a11.x * w11;
    r.y = a00.y * w00 + a01.y * w01 + a10.y * w10 + a11.y * w11;
    r.z = b00.x * w00 + b01.x * w01 + b10.x * w10 + b11.x * w11;
    r.w = b00.y * w00 + b01.y * w01 + b10.y * w10 + b11.y * w11;

    out[(size_t)idx * 8 + L] = r;
}

// ---------------- unsorted fallback (ws too small for bins) ----------------
__global__ __launch_bounds__(256) void grid_main(const float2* __restrict__ coords,
                                                 const uint2* __restrict__ tcb,
                                                 f32x4* __restrict__ out4, int S) {
    int t = blockIdx.x * 256 + threadIdx.x;
    if (t >= S * 8) return;
    int L = t & 7;
    int s = t >> 3;
    float2 c = coords[s];
    int   res   = c_res[L];
    float scale = c_scale[L];
    const uint2* __restrict__ base = tcb + c_cum[L];
    float px = (c.x + 1.0f) * scale;
    float py = (c.y + 1.0f) * scale;
    float xf = floorf(px), yf = floorf(py);
    float wx = px - xf,    wy = py - yf;
    int x0 = (int)xf, y0 = (int)yf;
    int xp = min(max(x0, 0), res - 2);  wx += (float)(x0 - xp);
    int yp = min(max(y0, 0), res - 2);  wy += (float)(y0 - yp);
    const uint2* r0 = base + yp * res + xp;
    u32x4 t0 = *(const u32x4*)r0;
    u32x4 t1 = *(const u32x4*)(r0 + res);
    float2 a00 = up_h2(t0.x), b00 = up_h2(t0.y);
    float2 a01 = up_h2(t0.z), b01 = up_h2(t0.w);
    float2 a10 = up_h2(t1.x), b10 = up_h2(t1.y);
    float2 a11 = up_h2(t1.z), b11 = up_h2(t1.w);
    float w00 = (1.0f - wx) * (1.0f - wy);
    float w01 = wx * (1.0f - wy);
    float w10 = (1.0f - wx) * wy;
    float w11 = wx * wy;
    f32x4 r;
    r.x = a00.x * w00 + a01.x * w01 + a10.x * w10 + a11.x * w11;
    r.y = a00.y * w00 + a01.y * w01 + a10.y * w10 + a11.y * w11;
    r.z = b00.x * w00 + b01.x * w01 + b10.x * w10 + b11.x * w11;
    r.w = b00.y * w00 + b01.y * w01 + b10.y * w10 + b11.y * w11;
    out4[t] = r;
}

// ---------------- generic levels fallback (levels != 8, raw fp32 cbs) ----------------
__global__ __launch_bounds__(256) void grid_generic(const float2* __restrict__ coords,
                                                    CbPtrs p, float4* __restrict__ out4,
                                                    int S, int levels) {
    int s = blockIdx.x * 256 + threadIdx.x;
    if (s >= S) return;
    float2 c = coords[s];
    for (int L = 0; L < levels; ++L) {
        int   res   = c_res[L];
        float scale = c_scale[L];
        float px = (c.x + 1.0f) * scale;
        float py = (c.y + 1.0f) * scale;
        float x0f = floorf(px), y0f = floorf(py);
        float wx = px - x0f,    wy = py - y0f;
        int rm1 = res - 1;
        int x0 = min(max((int)x0f, 0), rm1);
        int x1 = min(x0 + 1, rm1);
        int y0 = min(max((int)y0f, 0), rm1);
        int y1 = min(y0 + 1, rm1);
        int i00 = y0 * res + x0, i01 = y0 * res + x1, i10 = y1 * res + x0, i11 = y1 * res + x1;
        float w00 = (1.0f - wx) * (1.0f - wy);
        float w01 = wx * (1.0f - wy);
        float w10 = (1.0f - wx) * wy;
        float w11 = wx * wy;
        float4 r;
        const float* cb = p.cb[L];
        int rr = res * res;
        float* pr = &r.x;
#pragma unroll
        for (int f = 0; f < 4; ++f) {
            const float* cf = cb + f * rr;
            pr[f] = cf[i00] * w00 + cf[i01] * w01 + cf[i10] * w10 + cf[i11] * w11;
        }
        out4[(size_t)s * levels + L] = r;
    }
}

extern "C" void kernel_launch(void* const* d_in, const int* in_sizes, int n_in,
                              void* d_out, int out_size, void* d_ws, size_t ws_size,
                              hipStream_t stream) {
    const float2* coords = (const float2*)d_in[0];
    int S = in_sizes[0] / 2;                 // total samples B*N
    int levels = out_size / (S * 4);

    CbPtrs ptrs;
    for (int i = 0; i < NLEVELS; ++i) ptrs.cb[i] = (const float*)d_in[2 + i];

    // ws layout
    size_t tcb_bytes  = ((size_t)TOTAL_TEXELS * 8 + 255) & ~(size_t)255;
    size_t cnt_bytes  = 1024;                       // gcount[64] + gcursor[64]
    size_t crd_bytes  = (size_t)S * 8;
    size_t idx_bytes  = (size_t)S * 4;
    size_t need_sorted = tcb_bytes + cnt_bytes + crd_bytes + idx_bytes;

    char* ws = (char*)d_ws;
    uint2*  tcb     = (uint2*)ws;
    u32*    gcount  = (u32*)(ws + tcb_bytes);
    u32*    gcursor = gcount + NBANDS;
    float2* coordsS = (float2*)(ws + tcb_bytes + cnt_bytes);
    int*    idxS    = (int*)(ws + tcb_bytes + cnt_bytes + crd_bytes);

    if (levels != NLEVELS) {
        int blocks = (S + 255) / 256;
        grid_generic<<<blocks, 256, 0, stream>>>(coords, ptrs, (float4*)d_out, S, levels);
        return;
    }
    if (ws_size < tcb_bytes) {
        int blocks = (S + 255) / 256;
        grid_generic<<<blocks, 256, 0, stream>>>(coords, ptrs, (float4*)d_out, S, levels);
        return;
    }

    int tg = (TOTAL_TEXELS + 255) / 256;
    transpose_cbs<<<tg, 256, 0, stream>>>(ptrs, tcb, TOTAL_TEXELS);

    if (ws_size >= need_sorted) {
        int nchunk = (S + CHUNK - 1) / CHUNK;
        zero_counts<<<1, 64, 0, stream>>>(gcount);
        hist_kernel<<<512, 256, 0, stream>>>(coords, gcount, S);
        scan_kernel<<<1, 64, 0, stream>>>(gcount, gcursor);
        scatter_kernel<<<nchunk, 256, 0, stream>>>(coords, gcursor, coordsS, idxS, S);
        long long total = (long long)S * 8;
        int nb = (int)((total + 255) / 256);
        nb = ((nb + 7) / 8) * 8;             // multiple of 8 for bijective swizzle
        grid_sorted8<<<nb, 256, 0, stream>>>((const f32x2*)coordsS, idxS, tcb, (f32x4*)d_out, S);
    } else {
        long long total = (long long)S * 8;
        int blocks = (int)((total + 255) / 256);
        grid_main<<<blocks, 256, 0, stream>>>(coords, tcb, (f32x4*)d_out, S);
    }
}